// Round 1
// baseline (163.579 us; speedup 1.0000x reference)
//
#include <hip/hip_runtime.h>

static constexpr int B_ = 64, PAST = 128, FUTURE = 64, F_ = 51;
static constexpr int N1 = B_ * PAST;    // 8192
static constexpr int N2 = B_ * FUTURE;  // 4096
static constexpr int E1 = N1 * 16;      // 131072
static constexpr int E2 = N2 * 16;      // 65536
static constexpr int MAXDEG = 64;
static constexpr int CSR_TOT = E1 + N1 + E2 + N2 + FUTURE * PAST;  // 217088
static constexpr int NB_CSR = CSR_TOT / 256;                       // 848

// node feature t of _pre(): [emb0[c0] (16) | emb1[c1] (8) | emb2[c2] (24) | num (3)]
__device__ __forceinline__
float node_feat(const int* cat, const float* num, const float* e0, const float* e1,
                const float* e2, int n, int t) {
    if (t < 16) return e0[cat[n * 3 + 0] * 16 + t];
    if (t < 24) return e1[cat[n * 3 + 1] * 8 + (t - 16)];
    if (t < 48) return e2[cat[n * 3 + 2] * 24 + (t - 24)];
    return num[n * 3 + (t - 48)];
}

// K1 (fused): blocks [0,NB_CSR): CSR build + mask transpose (counts pre-zeroed by
// memset). Blocks [NB_CSR, NB_CSR+N1): past prep -> h1, asrc1, adst1, y1.
// Blocks [NB_CSR+N1, ...): future prep -> x2g, P2 = x2@W, h2base = x2[:,:50]@g2_lin.
__global__ __launch_bounds__(256) void k_prep(
        const int* __restrict__ cat1, const float* __restrict__ num1,
        const int* __restrict__ cat2, const float* __restrict__ num2,
        const float* __restrict__ emb0, const float* __restrict__ emb1,
        const float* __restrict__ emb2,
        const float* __restrict__ g1_lin, const float* __restrict__ g1_asrc,
        const float* __restrict__ g1_adst, const float* __restrict__ W,
        const float* __restrict__ g2_lin,
        const int* __restrict__ e1, const int* __restrict__ e2,
        const int* __restrict__ A,
        float* __restrict__ h1, float* __restrict__ asrc1, float* __restrict__ adst1,
        float* __restrict__ y1, float* __restrict__ x2g, float* __restrict__ P2,
        float* __restrict__ h2b,
        int* __restrict__ count1, int* __restrict__ slot1,
        int* __restrict__ count2, int* __restrict__ slot2, int* __restrict__ maskT) {
    int blk = blockIdx.x, t = threadIdx.x;
    if (blk < NB_CSR) {                           // CSR part (independent of prep)
        int i = blk * 256 + t;
        if (i < E1) {
            int src = e1[i], dst = e1[E1 + i];
            int pos = atomicAdd(&count1[dst], 1);
            if (pos < MAXDEG) slot1[dst * MAXDEG + pos] = src;
        } else if (i < E1 + N1) {
            int n = i - E1;
            int pos = atomicAdd(&count1[n], 1);
            if (pos < MAXDEG) slot1[n * MAXDEG + pos] = n;
        } else if (i < E1 + N1 + E2) {
            int k = i - E1 - N1;
            int src = e2[k], dst = e2[E2 + k];
            int pos = atomicAdd(&count2[dst], 1);
            if (pos < MAXDEG) slot2[dst * MAXDEG + pos] = src;
        } else if (i < E1 + N1 + E2 + N2) {
            int n = i - E1 - N1 - E2;
            int pos = atomicAdd(&count2[n], 1);
            if (pos < MAXDEG) slot2[n * MAXDEG + pos] = n;
        } else if (i < CSR_TOT) {
            int k = i - (E1 + N1 + E2 + N2);      // k = f*128 + p
            int f = k >> 7, pp = k & 127;
            maskT[k] = A[pp * 192 + PAST + f];
        }
        return;
    }
    __shared__ float xrow[F_];
    __shared__ float redS[200];
    __shared__ float redD[200];
    int rb = blk - NB_CSR;
    if (rb >= N1) {                               // future node
        int n = rb - N1;
        if (t < F_) {
            float xv = node_feat(cat2, num2, emb0, emb1, emb2, n, t);
            xrow[t] = xv;
            x2g[n * F_ + t] = xv;
        }
        __syncthreads();
        if (t < 64) {
            float acc = 0.f;
            for (int j = 0; j < 50; ++j) acc += xrow[j] * W[j * 64 + t];
            P2[n * 64 + t] = acc;
        } else if (t < 68) {                      // attention-independent part of h2
            int h = t - 64;
            float acc = 0.f;
            for (int j = 0; j < 50; ++j) acc += xrow[j] * g2_lin[j * 4 + h];
            h2b[n * 4 + h] = acc;
        }
        return;
    }
    int n = rb;                                   // past node
    if (t < F_) {
        float xv = node_feat(cat1, num1, emb0, emb1, emb2, n, t);
        xrow[t] = xv;
        if (t == 50) y1[n] = xv;                  // y_past = x[:, 50]
    }
    __syncthreads();
    if (t < 200) {
        float acc = 0.f;
        for (int j = 0; j < F_; ++j) acc += xrow[j] * g1_lin[j * 200 + t];
        h1[n * 200 + t] = acc;
        redS[t] = acc * g1_asrc[t];               // flat t == h*50+c
        redD[t] = acc * g1_adst[t];
    }
    __syncthreads();
    if (t < 4) {
        float s = 0.f;
        for (int c = 0; c < 50; ++c) s += redS[t * 50 + c];
        asrc1[n * 4 + t] = s;
    } else if (t < 8) {
        int h = t - 4;
        float s = 0.f;
        for (int c = 0; c < 50; ++c) s += redD[h * 50 + c];
        adst1[n * 4 + h] = s;
    }
}

// K2: GAT1 aggregation, one wave per dst node; fused x1 -> P projection.
// Writes P transposed per graph: P1T[b][k][p]  (enables float4 staging in k_attn)
// and the squared row norm n1w[n] = ||P1 row||^2 (norm-expansion trick).
__global__ __launch_bounds__(256) void k_gat1(
        const int* __restrict__ count1, const int* __restrict__ slot1,
        const float* __restrict__ h1, const float* __restrict__ asrc1,
        const float* __restrict__ adst1, const float* __restrict__ g1_b,
        const float* __restrict__ W, float* __restrict__ P1T,
        float* __restrict__ n1w) {
    __shared__ int    Ssrc[4][64];
    __shared__ float4 Sw[4][64];
    __shared__ float  Sx[4][64];
    int t = threadIdx.x, lane = t & 63, wv = t >> 6;
    int n = (blockIdx.x * 256 + t) >> 6;          // one node per wave (grid exact)
    int deg = min(count1[n], MAXDEG);
    int my_src = (lane < deg) ? slot1[n * MAXDEG + lane] : 0;
    float ad0 = adst1[n * 4 + 0], ad1 = adst1[n * 4 + 1];
    float ad2 = adst1[n * 4 + 2], ad3 = adst1[n * 4 + 3];
    float ex0 = 0.f, ex1 = 0.f, ex2 = 0.f, ex3 = 0.f;
    if (lane < deg) {
        float e0 = asrc1[my_src * 4 + 0] + ad0;
        float e1 = asrc1[my_src * 4 + 1] + ad1;
        float e2 = asrc1[my_src * 4 + 2] + ad2;
        float e3 = asrc1[my_src * 4 + 3] + ad3;
        e0 = e0 >= 0.f ? e0 : 0.2f * e0;  ex0 = __expf(e0);
        e1 = e1 >= 0.f ? e1 : 0.2f * e1;  ex1 = __expf(e1);
        e2 = e2 >= 0.f ? e2 : 0.2f * e2;  ex2 = __expf(e2);
        e3 = e3 >= 0.f ? e3 : 0.2f * e3;  ex3 = __expf(e3);
    }
    float s0 = ex0, s1 = ex1, s2 = ex2, s3 = ex3;
    #pragma unroll
    for (int m = 32; m >= 1; m >>= 1) {
        s0 += __shfl_xor(s0, m);
        s1 += __shfl_xor(s1, m);
        s2 += __shfl_xor(s2, m);
        s3 += __shfl_xor(s3, m);
    }
    Ssrc[wv][lane] = my_src;
    Sw[wv][lane] = make_float4(ex0 / (s0 + 1e-16f), ex1 / (s1 + 1e-16f),
                               ex2 / (s2 + 1e-16f), ex3 / (s3 + 1e-16f));
    __syncthreads();
    float acc0 = 0.f, acc1 = 0.f, acc2 = 0.f, acc3 = 0.f;
    for (int i = 0; i < deg; ++i) {
        int srci = Ssrc[wv][i];
        float4 w = Sw[wv][i];                     // broadcast, conflict-free
        if (lane < 50) {
            const float* hr = &h1[srci * 200];
            acc0 += w.x * hr[lane];
            acc1 += w.y * hr[50 + lane];
            acc2 += w.z * hr[100 + lane];
            acc3 += w.w * hr[150 + lane];
        }
    }
    if (lane < 50)
        Sx[wv][lane] = 0.25f * (acc0 + acc1 + acc2 + acc3) + g1_b[lane];
    __syncthreads();
    float a = 0.f;
    for (int j = 0; j < 50; ++j) a += Sx[wv][j] * W[j * 64 + lane];
    int b = n >> 7, p = n & 127;
    P1T[b * 8192 + lane * 128 + p] = a;           // transposed store [b][k][p]
    float sq = a * a;                             // ||P1 row||^2 via wave reduce
    #pragma unroll
    for (int m = 32; m >= 1; m >>= 1) sq += __shfl_xor(sq, m);
    if (lane == 0) n1w[n] = sq;
}

// K3: attention + tmp + h2 finalize. Grid = B*16 blocks (4 blocks/CU, 16 waves/CU);
// one f per wave. Norm expansion: alpha_p = 2*dot(P1_p,P2_f) - ||P1_p||^2
// (||P2_f||^2 dropped: constant per softmax row). Linear LDS [k][p]: float4
// staging writes and float2 column reads are both bank-conflict-free.
__global__ __launch_bounds__(256) void k_attn(
        const float* __restrict__ P1T, const float* __restrict__ P2,
        const int* __restrict__ maskT, const float* __restrict__ y1,
        const float* __restrict__ n1w, const float* __restrict__ h2b,
        const float* __restrict__ g2_lin, float* __restrict__ h2g) {
    __shared__ __align__(16) float P1s[8192];     // [k][p] linear
    __shared__ __align__(16) float ys[128];
    __shared__ __align__(16) float n1s[128];
    int b = blockIdx.x >> 4, fg = blockIdx.x & 15;
    int t = threadIdx.x, lane = t & 63, wv = t >> 6;
    const float4* src4 = (const float4*)(P1T + b * 8192);
    float4* dst4 = (float4*)P1s;
    #pragma unroll
    for (int i = 0; i < 8; ++i) dst4[t + i * 256] = src4[t + i * 256];
    if (t < 128) {
        ys[t]  = y1[b * 128 + t];
        n1s[t] = n1w[b * 128 + t];
    }
    __syncthreads();
    int f = (fg << 2) + wv;
    int q = b * 64 + f;
    float p2k = P2[q * 64 + lane];                // lane holds k-th component
    float dota = 0.f, dotb = 0.f;
    const float2* P12 = (const float2*)P1s;       // element (k, p=2*lane[+1])
    #pragma unroll
    for (int k = 0; k < 64; ++k) {
        float bk = __shfl(p2k, k);                // readlane after full unroll
        float2 v = P12[k * 64 + lane];
        dota += v.x * bk;
        dotb += v.y * bk;
    }
    int2  mm  = ((const int2*)maskT)[f * 64 + lane];   // mask for p=2*lane, 2*lane+1
    float2 nv = ((const float2*)n1s)[lane];
    float va = mm.x ? (2.f * dota - nv.x) : -1e30f;
    float vb = mm.y ? (2.f * dotb - nv.y) : -1e30f;
    float mx = fmaxf(va, vb);
    #pragma unroll
    for (int m = 32; m >= 1; m >>= 1) mx = fmaxf(mx, __shfl_xor(mx, m));
    float wa = mm.x ? __expf(va - mx) : 0.f;
    float wb = mm.y ? __expf(vb - mx) : 0.f;
    float2 yv = ((const float2*)ys)[lane];
    float sw = wa + wb;
    float sy = wa * yv.x + wb * yv.y;
    #pragma unroll
    for (int m = 32; m >= 1; m >>= 1) {
        sw += __shfl_xor(sw, m);
        sy += __shfl_xor(sy, m);
    }
    float tsh = sy / sw;
    if (lane < 4)                                 // h2 = h2base + tmp * g2_lin[50]
        h2g[q * 4 + lane] = h2b[q * 4 + lane] + tsh * g2_lin[50 * 4 + lane];
}

// K4: GAT2 aggregation (out_ch=1): one wave per dst node.
__global__ __launch_bounds__(256) void k_gat2(
        const int* __restrict__ count2, const int* __restrict__ slot2,
        const float* __restrict__ h2g, const float* __restrict__ g2_asrc,
        const float* __restrict__ g2_adst, const float* __restrict__ g2_b,
        float* __restrict__ out) {
    int wave = (blockIdx.x * blockDim.x + threadIdx.x) >> 6;
    int lane = threadIdx.x & 63;
    if (wave >= N2) return;
    int n = wave;
    int deg = min(count2[n], MAXDEG);
    int my_src = (lane < deg) ? slot2[n * MAXDEG + lane] : 0;
    float ex[4], nm[4], adterm[4], as[4];
    #pragma unroll
    for (int h = 0; h < 4; ++h) {
        as[h] = g2_asrc[h];
        adterm[h] = h2g[n * 4 + h] * g2_adst[h];
        ex[h] = 0.f; nm[h] = 0.f;
    }
    if (lane < deg) {
        #pragma unroll
        for (int h = 0; h < 4; ++h) {
            float hs = h2g[my_src * 4 + h];
            float e = hs * as[h] + adterm[h];
            e = e >= 0.f ? e : 0.2f * e;
            float xv = __expf(e);
            ex[h] = xv;
            nm[h] = xv * hs;
        }
    }
    #pragma unroll
    for (int m = 32; m >= 1; m >>= 1) {
        #pragma unroll
        for (int h = 0; h < 4; ++h) {
            ex[h] += __shfl_xor(ex[h], m);
            nm[h] += __shfl_xor(nm[h], m);
        }
    }
    if (lane == 0) {
        float o = 0.f;
        #pragma unroll
        for (int h = 0; h < 4; ++h) o += nm[h] / (ex[h] + 1e-16f);
        out[n] = 0.25f * o + g2_b[0];
    }
}

extern "C" void kernel_launch(void* const* d_in, const int* in_sizes, int n_in,
                              void* d_out, int out_size, void* d_ws, size_t ws_size,
                              hipStream_t stream) {
    const int*   cat1    = (const int*)  d_in[0];
    const float* num1    = (const float*)d_in[1];
    const int*   cat2    = (const int*)  d_in[2];
    const float* num2    = (const float*)d_in[3];
    const int*   e1      = (const int*)  d_in[4];
    const int*   e2      = (const int*)  d_in[5];
    const int*   A       = (const int*)  d_in[6];
    const float* emb0    = (const float*)d_in[7];
    const float* emb1    = (const float*)d_in[8];
    const float* emb2    = (const float*)d_in[9];
    const float* g1_lin  = (const float*)d_in[10];
    const float* g1_asrc = (const float*)d_in[11];
    const float* g1_adst = (const float*)d_in[12];
    const float* g1_b    = (const float*)d_in[13];
    const float* g2_lin  = (const float*)d_in[14];
    const float* g2_asrc = (const float*)d_in[15];
    const float* g2_adst = (const float*)d_in[16];
    const float* g2_b    = (const float*)d_in[17];
    const float* W       = (const float*)d_in[18];
    float* out = (float*)d_out;

    // workspace layout (fp32/int32 elements)
    int*   count1 = (int*)d_ws;                   // N1  (count1+count2 contiguous!)
    int*   count2 = count1 + N1;                  // N2
    int*   slot1  = count2 + N2;                  // N1*64
    int*   slot2  = slot1 + N1 * MAXDEG;          // N2*64
    int*   maskT  = slot2 + N2 * MAXDEG;          // 64*128
    float* h1     = (float*)(maskT + FUTURE * PAST);  // N1*200
    float* asrc1  = h1 + N1 * 200;                // N1*4
    float* adst1  = asrc1 + N1 * 4;               // N1*4
    float* y1     = adst1 + N1 * 4;               // N1
    float* x2g    = y1 + N1;                      // N2*51
    float* P1T    = x2g + N2 * F_;                // N1*64 as [b][k][p] (16B aligned)
    float* P2     = P1T + N1 * 64;                // N2*64
    float* h2g    = P2 + N2 * 64;                 // N2*4
    float* n1w    = h2g + N2 * 4;                 // N1
    float* h2b    = n1w + N1;                     // N2*4

    hipMemsetAsync(count1, 0, (N1 + N2) * sizeof(int), stream);
    k_prep<<<NB_CSR + N1 + N2, 256, 0, stream>>>(
        cat1, num1, cat2, num2, emb0, emb1, emb2, g1_lin, g1_asrc, g1_adst, W,
        g2_lin, e1, e2, A, h1, asrc1, adst1, y1, x2g, P2, h2b,
        count1, slot1, count2, slot2, maskT);
    k_gat1<<<N1 / 4, 256, 0, stream>>>(count1, slot1, h1, asrc1, adst1, g1_b, W,
                                       P1T, n1w);
    k_attn<<<B_ * 16, 256, 0, stream>>>(P1T, P2, maskT, y1, n1w, h2b, g2_lin, h2g);
    k_gat2<<<N2 / 4, 256, 0, stream>>>(count2, slot2, h2g, g2_asrc, g2_adst, g2_b, out);
}